// Round 6
// baseline (147.705 us; speedup 1.0000x reference)
//
#include <hip/hip_runtime.h>

typedef float f32x4 __attribute__((ext_vector_type(4)));
typedef short short8 __attribute__((ext_vector_type(8)));

#define DEVI static __device__ __forceinline__

DEVI ushort f2bf(float f) {
  unsigned u = __builtin_bit_cast(unsigned, f);
  u += 0x7fffu + ((u >> 16) & 1u);
  return (ushort)(u >> 16);
}

DEVI short8 pack8(float4 a, float4 b) {
  union { ushort u[8]; short8 v; } t;
  t.u[0] = f2bf(a.x); t.u[1] = f2bf(a.y); t.u[2] = f2bf(a.z); t.u[3] = f2bf(a.w);
  t.u[4] = f2bf(b.x); t.u[5] = f2bf(b.y); t.u[6] = f2bf(b.z); t.u[7] = f2bf(b.w);
  return t.v;
}

DEVI f32x4 MFMA16(short8 a, short8 b, f32x4 c) {
  return __builtin_amdgcn_mfma_f32_16x16x32_bf16(a, b, c, 0, 0, 0);
}

// async global->LDS DMA, 16B/lane; LDS dest is wave-uniform base (+lane*16 by HW)
DEVI void gld16(const ushort* g, ushort* l) {
  __builtin_amdgcn_global_load_lds(
      (const __attribute__((address_space(1))) unsigned int*)g,
      (__attribute__((address_space(3))) unsigned int*)l, 16, 0, 0);
}

// ---------------- fused prep: bias materialize + 3 bf16 converts ----------------
__global__ void prep_all(const float* __restrict__ table, const int* __restrict__ rel_idx,
                         float* __restrict__ bias,
                         const float* __restrict__ x, ushort* __restrict__ xbf,
                         const float* __restrict__ wq, ushort* __restrict__ wqb,
                         const float* __restrict__ wp, ushort* __restrict__ wpb) {
  const int bid = blockIdx.x, tid = threadIdx.x;
  if (bid < 2028) {
    int i = bid * 256 + tid;
    int k = i % 208;
    int t = i / 208;
    int q = t % 208;
    int h = t / 208;
    float v;
    if (k >= 197) v = -1e30f;
    else if (q == 0 || k == 0 || q >= 197) v = 0.0f;
    else v = table[rel_idx[(q - 1) * 196 + (k - 1)] * 12 + h];
    bias[i] = v;
  } else if (bid < 6756) {
    int i = (bid - 2028) * 256 + tid;
    float4 a = ((const float4*)x)[i * 2];
    float4 b = ((const float4*)x)[i * 2 + 1];
    ((short8*)xbf)[i] = pack8(a, b);
  } else if (bid < 7620) {
    int i = (bid - 6756) * 256 + tid;
    float4 a = ((const float4*)wq)[i * 2];
    float4 b = ((const float4*)wq)[i * 2 + 1];
    ((short8*)wqb)[i] = pack8(a, b);
  } else {
    int i = (bid - 7620) * 256 + tid;
    float4 a = ((const float4*)wp)[i * 2];
    float4 b = ((const float4*)wp)[i * 2 + 1];
    ((short8*)wpb)[i] = pack8(a, b);
  }
}

// ====== 256x256 8-phase GEMM (m201-style), BK=64, 2-buf LDS, vmcnt(2)@ph4/ph8 ======
// A-halves interleaved by m-frag parity (phase order (fh,kk)=(0,0),(1,0),(0,1),(1,1))
// so A regions free mid-tile -> 1-half-per-phase stage rotation fits 2 buffers.
// Swizzle: LDS cell (row, cg) holds global colgroup cg^(row&7); read col ^= ((row&7)<<3).
// Stage slots (iter i): ph1 A1[2i+1], ph2 B0[2i+1], ph3 B1[2i+1], ph4 A0[2i+2]+vmcnt(2),
//   ph5 A1[2i+2], ph6 B0[2i+2], ph7 B1[2i+2], ph8 A0[2i+3]+vmcnt(2).
// WAR: every stage lands >=1 trailing barrier after its region's last reader (verified
// per-phase). RAW: tile 2i+1 issued by ph3 -> vmcnt(2)@ph4 (ph4's own 2 loads ride);
// tile 2i+2 issued by ph7 -> vmcnt(2)@ph8.
#define BARRIER() { asm volatile("" ::: "memory"); __builtin_amdgcn_s_barrier(); asm volatile("" ::: "memory"); }
#define VMC(N) asm volatile("s_waitcnt vmcnt(" #N ")" ::: "memory")
#define NOP

template <int MODE, int NBN>
__launch_bounds__(512, 2)
__global__ void gemm8p(const ushort* __restrict__ A, const ushort* __restrict__ B,
                       ushort* __restrict__ q, ushort* __restrict__ k,
                       ushort* __restrict__ v,
                       const float* __restrict__ bprj, float* __restrict__ out) {
  __shared__ __align__(16) ushort AS[32768];  // [buf2][half2][128 rows][64 cols]
  __shared__ __align__(16) ushort BS[32768];

  const int tid = threadIdx.x;
  const int lane = tid & 63, wid = tid >> 6;
  const int wm = wid >> 2, wn = wid & 3;  // 2M x 4N waves
  const int l15 = lane & 15, l4 = lane >> 4;

  // bijective XCD swizzle (m204)
  const int nwg = gridDim.x;
  const int qc = nwg >> 3, rc = nwg & 7;
  const int xcd = blockIdx.x & 7, sub = blockIdx.x >> 3;
  const int wgid = (xcd < rc ? xcd * (qc + 1) : rc * (qc + 1) + (xcd - rc) * qc) + sub;
  const int bn = wgid % NBN, bm = wgid / NBN;

  // staging source pointers: thread covers half-local row rhl = wid*8 + lane/8 + j*64,
  // colgroup cg = lane&7; source col pre-swizzled: (cg ^ (rhl&7))*8.
  // A half h rows (interleaved): grow = (rhl>>4)*32 + h*16 + (rhl&15)
  // B half h rows (plain):       grow = h*128 + rhl
  const int lr = lane >> 3;
  const int cg = lane & 7;
  const ushort* pa[2][2];
  const ushort* pb[2][2];
#pragma unroll
  for (int h = 0; h < 2; h++) {
#pragma unroll
    for (int j = 0; j < 2; j++) {
      int rhl = wid * 8 + lr + j * 64;
      int scol = (cg ^ (rhl & 7)) * 8;
      long garow = (long)bm * 256 + (rhl >> 4) * 32 + h * 16 + (rhl & 15);
      if (garow > 12607) garow = 12607;
      pa[h][j] = A + garow * 768 + scol;
      pb[h][j] = B + ((long)bn * 256 + h * 128 + rhl) * 768 + scol;
    }
  }

  // fragment-read swizzled col offset (2-way bank conflict = free)
  const int cs0 = (l4 * 8) ^ ((l15 & 7) << 3);

  f32x4 acc[8][4];
#pragma unroll
  for (int m = 0; m < 8; m++)
#pragma unroll
    for (int n = 0; n < 4; n++) acc[m][n] = (f32x4)0.0f;

#define SA(BUF, H, KT) { gld16(pa[H][0] + (KT) * 64, AS + (BUF) * 16384 + (H) * 8192 + wid * 512);        \
                         gld16(pa[H][1] + (KT) * 64, AS + (BUF) * 16384 + (H) * 8192 + wid * 512 + 4096); }
#define SB(BUF, H, KT) { gld16(pb[H][0] + (KT) * 64, BS + (BUF) * 16384 + (H) * 8192 + wid * 512);        \
                         gld16(pb[H][1] + (KT) * 64, BS + (BUF) * 16384 + (H) * 8192 + wid * 512 + 4096); }

#define PHASE(BUF, FH, KK, STG, WAITC)                                                        \
  {                                                                                           \
    short8 af[4], bv[4];                                                                      \
    const int cko = cs0 ^ ((KK) << 5);                                                        \
    _Pragma("unroll") for (int j = 0; j < 4; j++)                                             \
      af[j] = *(const short8*)&AS[(BUF) * 16384 + (FH) * 8192 + (wm * 4 + j) * 1024 +         \
                                  l15 * 64 + cko];                                            \
    _Pragma("unroll") for (int n = 0; n < 4; n++)                                             \
      bv[n] = *(const short8*)&BS[(BUF) * 16384 + (wn >> 1) * 8192 +                          \
                                  ((wn & 1) * 64 + n * 16 + l15) * 64 + cko];                 \
    STG;                                                                                      \
    WAITC;                                                                                    \
    BARRIER();                                                                                \
    __builtin_amdgcn_s_setprio(1);                                                            \
    _Pragma("unroll") for (int j = 0; j < 4; j++)                                             \
      _Pragma("unroll") for (int n = 0; n < 4; n++)                                           \
        acc[(FH) + 2 * j][n] = MFMA16(af[j], bv[n], acc[(FH) + 2 * j][n]);                    \
    __builtin_amdgcn_s_setprio(0);                                                            \
    BARRIER();                                                                                \
  }

  // prologue: tile0 all halves + A-h0[1]; wait tile0 landed (A-h0[1] rides)
  SA(0, 0, 0) SA(0, 1, 0) SB(0, 0, 0) SB(0, 1, 0) SA(1, 0, 1)
  VMC(2);
  BARRIER();

  for (int i = 0; i < 5; ++i) {
    const int t1 = 2 * i + 1, t2 = 2 * i + 2, t3 = 2 * i + 3;
    PHASE(0, 0, 0, SA(1, 1, t1), NOP)
    PHASE(0, 1, 0, SB(1, 0, t1), NOP)
    PHASE(0, 0, 1, SB(1, 1, t1), NOP)
    PHASE(0, 1, 1, SA(0, 0, t2), VMC(2))
    PHASE(1, 0, 0, SA(0, 1, t2), NOP)
    PHASE(1, 1, 0, SB(0, 0, t2), NOP)
    PHASE(1, 0, 1, SB(0, 1, t2), NOP)
    PHASE(1, 1, 1, SA(1, 0, t3), VMC(2))
  }
  // tail iteration: tiles 10 (buf0) and 11 (buf1); stage only tile 11 remainder
  PHASE(0, 0, 0, SA(1, 1, 11), NOP)
  PHASE(0, 1, 0, SB(1, 0, 11), NOP)
  PHASE(0, 0, 1, SB(1, 1, 11), NOP)
  PHASE(0, 1, 1, NOP, VMC(0))
  PHASE(1, 0, 0, NOP, NOP)
  PHASE(1, 1, 0, NOP, NOP)
  PHASE(1, 0, 1, NOP, NOP)
  PHASE(1, 1, 1, NOP, NOP)

  // ---------------- epilogue ----------------
  if (MODE == 0) {
    const int c6 = (bn * 256 + wn * 64) >> 6;  // 64-col group in [0,36)
    const int s = c6 / 12, hh = c6 % 12;
    ushort* dst = (s == 0) ? q : ((s == 1) ? k : v);
    const float qs = (s == 0) ? 0.125f : 1.0f;
#pragma unroll
    for (int f = 0; f < 8; f++) {
#pragma unroll
      for (int r = 0; r < 4; r++) {
        int gm = bm * 256 + wm * 128 + f * 16 + l4 * 4 + r;
        if (gm >= 12608) continue;
        int b = gm / 197;
        int ns = gm - b * 197;
        size_t base = (size_t)((b * 12 + hh) * 197 + ns) * 64;
#pragma unroll
        for (int n = 0; n < 4; n++)
          dst[base + n * 16 + l15] = f2bf(acc[f][n][r] * qs);
      }
    }
  } else {
    float bb[4];
#pragma unroll
    for (int n = 0; n < 4; n++) bb[n] = bprj[bn * 256 + wn * 64 + n * 16 + l15];
#pragma unroll
    for (int f = 0; f < 8; f++) {
#pragma unroll
      for (int r = 0; r < 4; r++) {
        int gm = bm * 256 + wm * 128 + f * 16 + l4 * 4 + r;
        if (gm >= 12608) continue;
#pragma unroll
        for (int n = 0; n < 4; n++)
          out[(size_t)gm * 768 + bn * 256 + wn * 64 + n * 16 + l15] = acc[f][n][r] + bb[n];
      }
    }
  }
#undef SA
#undef SB
#undef PHASE
}

// ---------------- fused attention per (b,h) ----------------
__launch_bounds__(512)
__global__ void attn(const ushort* __restrict__ qws, const ushort* __restrict__ kws,
                     const ushort* __restrict__ vws, const float* __restrict__ biasws,
                     ushort* __restrict__ aout) {
  __shared__ __align__(16) ushort Ks[208 * 72];
  __shared__ __align__(16) ushort Vt[64 * 232];
  __shared__ __align__(16) ushort Ps[8 * 16 * 232];

  const int bh = blockIdx.x;
  const int b = bh / 12;
  const int h = bh - b * 12;
  const ushort* qb = qws + (size_t)bh * 197 * 64;
  const ushort* kb = kws + (size_t)bh * 197 * 64;
  const ushort* vb = vws + (size_t)bh * 197 * 64;

  const int tid = threadIdx.x;
  const int lane = tid & 63, wid = tid >> 6;
  const int l15 = lane & 15, l4 = lane >> 4;

  for (int c = tid; c < 208 * 8; c += 512) {
    int n = c >> 3, col = (c & 7) << 3;
    short8 v = (short8)0;
    if (n < 197) v = *(const short8*)(kb + n * 64 + col);
    *(short8*)&Ks[n * 72 + col] = v;
  }
  for (int c = tid; c < 224 * 8; c += 512) {
    int n = c % 224;
    int d0 = (c / 224) << 3;
    ushort tmp[8] = {0, 0, 0, 0, 0, 0, 0, 0};
    if (n < 197) {
      short8 v = *(const short8*)(vb + n * 64 + d0);
#pragma unroll
      for (int j = 0; j < 8; j++) tmp[j] = (ushort)v[j];
    }
#pragma unroll
    for (int j = 0; j < 8; j++) Vt[(d0 + j) * 232 + n] = tmp[j];
  }
  __syncthreads();

  ushort* pb = &Ps[wid * (16 * 232)];
  const float* biasb = biasws + (size_t)h * 208 * 208;

  for (int t = wid; t < 13; t += 8) {
    const int q0 = t * 16;
    int qr = q0 + l15; if (qr > 196) qr = 196;
    short8 aq0 = *(const short8*)(qb + qr * 64 + (l4 << 3));
    short8 aq1 = *(const short8*)(qb + qr * 64 + 32 + (l4 << 3));

    f32x4 sc[13];
    __builtin_amdgcn_s_setprio(1);
#pragma unroll
    for (int ct = 0; ct < 13; ct++) {
      short8 b0 = *(const short8*)&Ks[(ct * 16 + l15) * 72 + (l4 << 3)];
      short8 b1 = *(const short8*)&Ks[(ct * 16 + l15) * 72 + 32 + (l4 << 3)];
      f32x4 s = (f32x4)0.0f;
      s = MFMA16(aq0, b0, s);
      s = MFMA16(aq1, b1, s);
      sc[ct] = s;
    }
    __builtin_amdgcn_s_setprio(0);

    float mx[4] = {-1e38f, -1e38f, -1e38f, -1e38f};
#pragma unroll
    for (int ct = 0; ct < 13; ct++) {
#pragma unroll
      for (int r = 0; r < 4; r++) {
        float bv = biasb[(q0 + l4 * 4 + r) * 208 + ct * 16 + l15];
        float v = sc[ct][r] + bv;
        sc[ct][r] = v;
        mx[r] = fmaxf(mx[r], v);
      }
    }
#pragma unroll
    for (int r = 0; r < 4; r++) {
      mx[r] = fmaxf(mx[r], __shfl_xor(mx[r], 1));
      mx[r] = fmaxf(mx[r], __shfl_xor(mx[r], 2));
      mx[r] = fmaxf(mx[r], __shfl_xor(mx[r], 4));
      mx[r] = fmaxf(mx[r], __shfl_xor(mx[r], 8));
    }
    float sum[4] = {0.f, 0.f, 0.f, 0.f};
#pragma unroll
    for (int ct = 0; ct < 13; ct++) {
#pragma unroll
      for (int r = 0; r < 4; r++) {
        float p = __expf(sc[ct][r] - mx[r]);
        sc[ct][r] = p;
        sum[r] += p;
      }
    }
#pragma unroll
    for (int r = 0; r < 4; r++) {
      sum[r] += __shfl_xor(sum[r], 1);
      sum[r] += __shfl_xor(sum[r], 2);
      sum[r] += __shfl_xor(sum[r], 4);
      sum[r] += __shfl_xor(sum[r], 8);
    }

#pragma unroll
    for (int ct = 0; ct < 13; ct++)
#pragma unroll
      for (int r = 0; r < 4; r++)
        pb[(l4 * 4 + r) * 232 + ct * 16 + l15] = f2bf(sc[ct][r]);
#pragma unroll
    for (int r = 0; r < 4; r++)
      pb[(l4 * 4 + r) * 232 + 208 + l15] = 0;

    short8 pa[7];
#pragma unroll
    for (int kk = 0; kk < 7; kk++)
      pa[kk] = *(const short8*)&pb[l15 * 232 + kk * 32 + (l4 << 3)];
    f32x4 o[4];
    __builtin_amdgcn_s_setprio(1);
#pragma unroll
    for (int dt = 0; dt < 4; dt++) {
      f32x4 acc = (f32x4)0.0f;
#pragma unroll
      for (int kk = 0; kk < 7; kk++) {
        short8 bv = *(const short8*)&Vt[(dt * 16 + l15) * 232 + kk * 32 + (l4 << 3)];
        acc = MFMA16(pa[kk], bv, acc);
      }
      o[dt] = acc;
    }
    __builtin_amdgcn_s_setprio(0);

    float rs[4];
#pragma unroll
    for (int r = 0; r < 4; r++) rs[r] = 1.0f / sum[r];
#pragma unroll
    for (int dt = 0; dt < 4; dt++) {
#pragma unroll
      for (int r = 0; r < 4; r++) {
        int row = q0 + l4 * 4 + r;
        if (row < 197) {
          float v = o[dt][r] * rs[r];
          aout[(size_t)(b * 197 + row) * 768 + h * 64 + dt * 16 + l15] = f2bf(v);
        }
      }
    }
  }
}

extern "C" void kernel_launch(void* const* d_in, const int* in_sizes, int n_in,
                              void* d_out, int out_size, void* d_ws, size_t ws_size,
                              hipStream_t stream) {
  const float* x      = (const float*)d_in[0];
  const float* w_qkv  = (const float*)d_in[1];
  const float* w_proj = (const float*)d_in[2];
  const float* b_proj = (const float*)d_in[3];
  const float* rpb    = (const float*)d_in[4];
  const int*   relidx = (const int*)d_in[5];
  float* out = (float*)d_out;

  char* ws = (char*)d_ws;
  const size_t HB = (size_t)12608 * 768 * 2;  // 19,365,888 B
  ushort* xbf   = (ushort*)(ws);              // aliased by aout after qkv is consumed
  ushort* qws   = (ushort*)(ws + HB);
  ushort* kws   = (ushort*)(ws + 2 * HB);
  ushort* vws   = (ushort*)(ws + 3 * HB);
  float*  bias  = (float*)(ws + 4 * HB);                       // 2,076,672 B
  ushort* wqkvb = (ushort*)(ws + 4 * HB + 2076672);            // 3,538,944 B
  ushort* wprjb = (ushort*)(ws + 4 * HB + 2076672 + 3538944);  // 1,179,648 B
  ushort* aout  = xbf;

  hipLaunchKernelGGL(prep_all, dim3(7908), dim3(256), 0, stream,
                     rpb, relidx, bias, x, xbf, w_qkv, wqkvb, w_proj, wprjb);
  hipLaunchKernelGGL((gemm8p<0, 9>), dim3(9 * 50), dim3(512), 0, stream,
                     xbf, wqkvb, qws, kws, vws, nullptr, nullptr);
  hipLaunchKernelGGL(attn, dim3(768), dim3(512), 0, stream, qws, kws, vws, bias, aout);
  hipLaunchKernelGGL((gemm8p<1, 3>), dim3(3 * 50), dim3(512), 0, stream,
                     aout, wprjb, nullptr, nullptr, nullptr, b_proj, out);
}

// Round 7
// 137.226 us; speedup vs baseline: 1.0764x; 1.0764x over previous
//
#include <hip/hip_runtime.h>

typedef float f32x4 __attribute__((ext_vector_type(4)));
typedef short short8 __attribute__((ext_vector_type(8)));

#define DEVI static __device__ __forceinline__

DEVI ushort f2bf(float f) {
  unsigned u = __builtin_bit_cast(unsigned, f);
  u += 0x7fffu + ((u >> 16) & 1u);
  return (ushort)(u >> 16);
}

DEVI short8 pack8(float4 a, float4 b) {
  union { ushort u[8]; short8 v; } t;
  t.u[0] = f2bf(a.x); t.u[1] = f2bf(a.y); t.u[2] = f2bf(a.z); t.u[3] = f2bf(a.w);
  t.u[4] = f2bf(b.x); t.u[5] = f2bf(b.y); t.u[6] = f2bf(b.z); t.u[7] = f2bf(b.w);
  return t.v;
}

DEVI f32x4 MFMA16(short8 a, short8 b, f32x4 c) {
  return __builtin_amdgcn_mfma_f32_16x16x32_bf16(a, b, c, 0, 0, 0);
}

// async global->LDS DMA, 16B/lane; LDS dest is wave-uniform base (+lane*16 by HW)
DEVI void gld16(const ushort* g, ushort* l) {
  __builtin_amdgcn_global_load_lds(
      (const __attribute__((address_space(1))) unsigned int*)g,
      (__attribute__((address_space(3))) unsigned int*)l, 16, 0, 0);
}

#define VMC0() asm volatile("s_waitcnt vmcnt(0)" ::: "memory")
#define LGK0() asm volatile("s_waitcnt lgkmcnt(0)" ::: "memory")

// ---------------- fused prep: bias materialize + 3 bf16 converts ----------------
__global__ void prep_all(const float* __restrict__ table, const int* __restrict__ rel_idx,
                         float* __restrict__ bias,
                         const float* __restrict__ x, ushort* __restrict__ xbf,
                         const float* __restrict__ wq, ushort* __restrict__ wqb,
                         const float* __restrict__ wp, ushort* __restrict__ wpb) {
  const int bid = blockIdx.x, tid = threadIdx.x;
  if (bid < 2028) {
    int i = bid * 256 + tid;
    int k = i % 208;
    int t = i / 208;
    int q = t % 208;
    int h = t / 208;
    float v;
    if (k >= 197) v = -1e30f;
    else if (q == 0 || k == 0 || q >= 197) v = 0.0f;
    else v = table[rel_idx[(q - 1) * 196 + (k - 1)] * 12 + h];
    bias[i] = v;
  } else if (bid < 6756) {
    int i = (bid - 2028) * 256 + tid;
    float4 a = ((const float4*)x)[i * 2];
    float4 b = ((const float4*)x)[i * 2 + 1];
    ((short8*)xbf)[i] = pack8(a, b);
  } else if (bid < 7620) {
    int i = (bid - 6756) * 256 + tid;
    float4 a = ((const float4*)wq)[i * 2];
    float4 b = ((const float4*)wq)[i * 2 + 1];
    ((short8*)wqb)[i] = pack8(a, b);
  } else {
    int i = (bid - 7620) * 256 + tid;
    float4 a = ((const float4*)wp)[i * 2];
    float4 b = ((const float4*)wp)[i * 2 + 1];
    ((short8*)wpb)[i] = pack8(a, b);
  }
}

// ====== QKV: 256x256 tile, BK=64, 2-phase dbuf (128KB LDS), drain-0 ledger ======
// Same proven round-4 ledger, bigger tile + K-step: 12 steps, 64 MFMA/step/wave.
// Swizzle both-sides: LDS[row][cg] = global[row][cg ^ (row&7)] (colgroups of 8);
// fragment read colgroup (l4 + kk*4) ^ (l15&7) -> 2-way bank conflict (free).
template <int NBN>
__launch_bounds__(512)
__global__ void qkv256(const ushort* __restrict__ A, const ushort* __restrict__ B,
                       ushort* __restrict__ q, ushort* __restrict__ k,
                       ushort* __restrict__ v) {
  __shared__ __align__(16) ushort AS[2][16384];  // [256 rows][64 cols]
  __shared__ __align__(16) ushort BS[2][16384];

  const int tid = threadIdx.x;
  const int lane = tid & 63, wid = tid >> 6;
  const int wm = wid >> 2, wn = wid & 3;  // 2M x 4N waves, wave tile 128x64
  const int l15 = lane & 15, l4 = lane >> 4;

  // bijective XCD swizzle (m204)
  const int nwg = gridDim.x;
  const int qc = nwg >> 3, rc = nwg & 7;
  const int xcd = blockIdx.x & 7, sub = blockIdx.x >> 3;
  const int wgid = (xcd < rc ? xcd * (qc + 1) : rc * (qc + 1) + (xcd - rc) * qc) + sub;
  const int bn = wgid % NBN, bm = wgid / NBN;

  // staging: tile = 32 chunks of 1KB (8 rows each); wave stages chunks wid*4..wid*4+3
  // chunk c, lane: row = c*8 + (lane>>3), colgroup cg = lane&7, source col (cg^(row&7))*8
  const ushort* pa[4];
  const ushort* pb[4];
  int ldsoff[4];
#pragma unroll
  for (int j = 0; j < 4; j++) {
    int c = wid * 4 + j;
    int row = c * 8 + (lane >> 3);
    int scol = ((lane & 7) ^ (row & 7)) << 3;
    long gra = (long)bm * 256 + row;
    if (gra > 12607) gra = 12607;
    pa[j] = A + gra * 768 + scol;
    pb[j] = B + ((long)bn * 256 + row) * 768 + scol;
    ldsoff[j] = c * 512;
  }

  // fragment-read swizzled colgroup offsets (elems) for kk=0,1; row dep = l15&7 only
  const int xk0 = ((l4 ^ (l15 & 7)) << 3);
  const int xk1 = (((l4 + 4) ^ (l15 & 7)) << 3);

  f32x4 acc[8][4];
#pragma unroll
  for (int m = 0; m < 8; m++)
#pragma unroll
    for (int n = 0; n < 4; n++) acc[m][n] = (f32x4)0.0f;

#define STAGE(BUF, KO)                                            \
  { _Pragma("unroll") for (int j = 0; j < 4; j++) {               \
      gld16(pa[j] + (KO), &AS[BUF][ldsoff[j]]);                   \
      gld16(pb[j] + (KO), &BS[BUF][ldsoff[j]]);                   \
    } }

#define COMPUTE(BUF)                                                        \
  { _Pragma("unroll") for (int kk = 0; kk < 2; kk++) {                      \
      const int xk = kk ? xk1 : xk0;                                        \
      short8 af[8], bv[4];                                                  \
      _Pragma("unroll") for (int m = 0; m < 8; m++)                         \
        af[m] = *(const short8*)&AS[BUF][(wm * 128 + m * 16 + l15) * 64 + xk]; \
      _Pragma("unroll") for (int n = 0; n < 4; n++)                         \
        bv[n] = *(const short8*)&BS[BUF][(wn * 64 + n * 16 + l15) * 64 + xk];  \
      __builtin_amdgcn_s_setprio(1);                                        \
      _Pragma("unroll") for (int m = 0; m < 8; m++)                         \
        _Pragma("unroll") for (int n = 0; n < 4; n++)                       \
          acc[m][n] = MFMA16(af[m], bv[n], acc[m][n]);                      \
      __builtin_amdgcn_s_setprio(0);                                        \
    } }

  STAGE(0, 0)
  // ledger (12 K-tiles): top of iter t -> vmcnt(0) drains stage-t (issued last
  // iter), lgkm(0) finishes my reads of buf[t-1&1]; barrier makes both global;
  // STAGE(t+1) then safely overwrites buf[(t+1)&1]; COMPUTE(t&1) reads landed data.
  for (int t = 0; t < 11; ++t) {
    VMC0(); LGK0();
    __builtin_amdgcn_s_barrier();
    __builtin_amdgcn_sched_barrier(0);
    STAGE((t + 1) & 1, (t + 1) * 64)
    COMPUTE(t & 1)
  }
  VMC0(); LGK0();
  __builtin_amdgcn_s_barrier();
  __builtin_amdgcn_sched_barrier(0);
  COMPUTE(1)

  // epilogue: scatter q/k/v per head (col group of 64 = one head slice)
  const int c6 = (bn * 256 + wn * 64) >> 6;  // in [0,36)
  const int s = c6 / 12, hh = c6 % 12;
  ushort* dst = (s == 0) ? q : ((s == 1) ? k : v);
  const float qs = (s == 0) ? 0.125f : 1.0f;
#pragma unroll
  for (int f = 0; f < 8; f++) {
#pragma unroll
    for (int r = 0; r < 4; r++) {
      int gm = bm * 256 + wm * 128 + f * 16 + l4 * 4 + r;
      if (gm >= 12608) continue;
      int b = gm / 197;
      int ns = gm - b * 197;
      size_t base = (size_t)((b * 12 + hh) * 197 + ns) * 64;
#pragma unroll
      for (int n = 0; n < 4; n++)
        dst[base + n * 16 + l15] = f2bf(acc[f][n][r] * qs);
    }
  }
#undef STAGE
#undef COMPUTE
}

// ====== Proj: 128x128 GEMM, BK=32, dbuf (32KB), round-4 structure ======
__launch_bounds__(256, 4)
__global__ void proj128(const ushort* __restrict__ A, const ushort* __restrict__ B,
                        const float* __restrict__ bprj, float* __restrict__ out) {
  __shared__ __align__(16) ushort As[2][4096];
  __shared__ __align__(16) ushort Bs[2][4096];

  const int tid = threadIdx.x;
  const int lane = tid & 63, wid = tid >> 6;
  const int wm = wid >> 1, wn = wid & 1;
  const int l15 = lane & 15, l4 = lane >> 4;

  const int nwg = gridDim.x;
  const int qc = nwg >> 3, rc = nwg & 7;
  const int xcd = blockIdx.x & 7, sub = blockIdx.x >> 3;
  const int wgid = (xcd < rc ? xcd * (qc + 1) : rc * (qc + 1) + (xcd - rc) * qc) + sub;
  const int bn = wgid % 6, bm = wgid / 6;

  const int c0 = wid * 2, c1 = wid * 2 + 1;
  const int r0 = c0 * 16 + (lane >> 2);
  const int r1 = c1 * 16 + (lane >> 2);
  const int g = lane & 3;
  const int col0 = (g << 3) ^ ((r0 & 6) << 2);
  const int col1 = (g << 3) ^ ((r1 & 6) << 2);
  long ar0 = bm * 128 + r0; if (ar0 > 12607) ar0 = 12607;
  long ar1 = bm * 128 + r1; if (ar1 > 12607) ar1 = 12607;
  const ushort* pA0 = A + ar0 * 768 + col0;
  const ushort* pA1 = A + ar1 * 768 + col1;
  const ushort* pB0 = B + (size_t)(bn * 128 + r0) * 768 + col0;
  const ushort* pB1 = B + (size_t)(bn * 128 + r1) * 768 + col1;

  const int xk = (l4 * 8) ^ ((l15 & 6) << 2);
  int aoff[4], boff[4];
#pragma unroll
  for (int m = 0; m < 4; m++) aoff[m] = (wm * 64 + m * 16 + l15) * 32 + xk;
#pragma unroll
  for (int n = 0; n < 4; n++) boff[n] = (wn * 64 + n * 16 + l15) * 32 + xk;

  f32x4 acc[4][4];
#pragma unroll
  for (int m = 0; m < 4; m++)
#pragma unroll
    for (int n = 0; n < 4; n++) acc[m][n] = (f32x4)0.0f;

#define STAGE(BUF, KO)                          \
  gld16(pA0 + (KO), &As[BUF][c0 * 512]);        \
  gld16(pA1 + (KO), &As[BUF][c1 * 512]);        \
  gld16(pB0 + (KO), &Bs[BUF][c0 * 512]);        \
  gld16(pB1 + (KO), &Bs[BUF][c1 * 512]);

#define COMPUTE(BUF)                                                \
  {                                                                 \
    short8 af[4], bv[4];                                            \
    _Pragma("unroll") for (int m = 0; m < 4; m++)                   \
        af[m] = *(const short8*)&As[BUF][aoff[m]];                  \
    _Pragma("unroll") for (int n = 0; n < 4; n++)                   \
        bv[n] = *(const short8*)&Bs[BUF][boff[n]];                  \
    __builtin_amdgcn_s_setprio(1);                                  \
    _Pragma("unroll") for (int m = 0; m < 4; m++)                   \
        _Pragma("unroll") for (int n = 0; n < 4; n++)               \
            acc[m][n] = MFMA16(af[m], bv[n], acc[m][n]);            \
    __builtin_amdgcn_s_setprio(0);                                  \
  }

  STAGE(0, 0)
  for (int t = 0; t < 23; ++t) {
    VMC0(); LGK0();
    __builtin_amdgcn_s_barrier();
    __builtin_amdgcn_sched_barrier(0);
    STAGE((t + 1) & 1, (t + 1) * 32)
    COMPUTE(t & 1)
  }
  VMC0(); LGK0();
  __builtin_amdgcn_s_barrier();
  __builtin_amdgcn_sched_barrier(0);
  COMPUTE(1)

  float bb[4];
#pragma unroll
  for (int n = 0; n < 4; n++) bb[n] = bprj[bn * 128 + wn * 64 + n * 16 + l15];
#pragma unroll
  for (int m = 0; m < 4; m++) {
#pragma unroll
    for (int r = 0; r < 4; r++) {
      int gm = bm * 128 + wm * 64 + m * 16 + l4 * 4 + r;
      if (gm >= 12608) continue;
#pragma unroll
      for (int n = 0; n < 4; n++)
        out[(size_t)gm * 768 + bn * 128 + wn * 64 + n * 16 + l15] = acc[m][n][r] + bb[n];
    }
  }
#undef STAGE
#undef COMPUTE
}

// ---------------- fused attention per (b,h) ----------------
__launch_bounds__(512)
__global__ void attn(const ushort* __restrict__ qws, const ushort* __restrict__ kws,
                     const ushort* __restrict__ vws, const float* __restrict__ biasws,
                     ushort* __restrict__ aout) {
  __shared__ __align__(16) ushort Ks[208 * 72];
  __shared__ __align__(16) ushort Vt[64 * 232];
  __shared__ __align__(16) ushort Ps[8 * 16 * 232];

  const int bh = blockIdx.x;
  const int b = bh / 12;
  const int h = bh - b * 12;
  const ushort* qb = qws + (size_t)bh * 197 * 64;
  const ushort* kb = kws + (size_t)bh * 197 * 64;
  const ushort* vb = vws + (size_t)bh * 197 * 64;

  const int tid = threadIdx.x;
  const int lane = tid & 63, wid = tid >> 6;
  const int l15 = lane & 15, l4 = lane >> 4;

  for (int c = tid; c < 208 * 8; c += 512) {
    int n = c >> 3, col = (c & 7) << 3;
    short8 v = (short8)0;
    if (n < 197) v = *(const short8*)(kb + n * 64 + col);
    *(short8*)&Ks[n * 72 + col] = v;
  }
  for (int c = tid; c < 224 * 8; c += 512) {
    int n = c % 224;
    int d0 = (c / 224) << 3;
    ushort tmp[8] = {0, 0, 0, 0, 0, 0, 0, 0};
    if (n < 197) {
      short8 v = *(const short8*)(vb + n * 64 + d0);
#pragma unroll
      for (int j = 0; j < 8; j++) tmp[j] = (ushort)v[j];
    }
#pragma unroll
    for (int j = 0; j < 8; j++) Vt[(d0 + j) * 232 + n] = tmp[j];
  }
  __syncthreads();

  ushort* pb = &Ps[wid * (16 * 232)];
  const float* biasb = biasws + (size_t)h * 208 * 208;

  for (int t = wid; t < 13; t += 8) {
    const int q0 = t * 16;
    int qr = q0 + l15; if (qr > 196) qr = 196;
    short8 aq0 = *(const short8*)(qb + qr * 64 + (l4 << 3));
    short8 aq1 = *(const short8*)(qb + qr * 64 + 32 + (l4 << 3));

    f32x4 sc[13];
    __builtin_amdgcn_s_setprio(1);
#pragma unroll
    for (int ct = 0; ct < 13; ct++) {
      short8 b0 = *(const short8*)&Ks[(ct * 16 + l15) * 72 + (l4 << 3)];
      short8 b1 = *(const short8*)&Ks[(ct * 16 + l15) * 72 + 32 + (l4 << 3)];
      f32x4 s = (f32x4)0.0f;
      s = MFMA16(aq0, b0, s);
      s = MFMA16(aq1, b1, s);
      sc[ct] = s;
    }
    __builtin_amdgcn_s_setprio(0);

    float mx[4] = {-1e38f, -1e38f, -1e38f, -1e38f};
#pragma unroll
    for (int ct = 0; ct < 13; ct++) {
#pragma unroll
      for (int r = 0; r < 4; r++) {
        float bv = biasb[(q0 + l4 * 4 + r) * 208 + ct * 16 + l15];
        float v = sc[ct][r] + bv;
        sc[ct][r] = v;
        mx[r] = fmaxf(mx[r], v);
      }
    }
#pragma unroll
    for (int r = 0; r < 4; r++) {
      mx[r] = fmaxf(mx[r], __shfl_xor(mx[r], 1));
      mx[r] = fmaxf(mx[r], __shfl_xor(mx[r], 2));
      mx[r] = fmaxf(mx[r], __shfl_xor(mx[r], 4));
      mx[r] = fmaxf(mx[r], __shfl_xor(mx[r], 8));
    }
    float sum[4] = {0.f, 0.f, 0.f, 0.f};
#pragma unroll
    for (int ct = 0; ct < 13; ct++) {
#pragma unroll
      for (int r = 0; r < 4; r++) {
        float p = __expf(sc[ct][r] - mx[r]);
        sc[ct][r] = p;
        sum[r] += p;
      }
    }
#pragma unroll
    for (int r = 0; r < 4; r++) {
      sum[r] += __shfl_xor(sum[r], 1);
      sum[r] += __shfl_xor(sum[r], 2);
      sum[r] += __shfl_xor(sum[r], 4);
      sum[r] += __shfl_xor(sum[r], 8);
    }

#pragma unroll
    for (int ct = 0; ct < 13; ct++)
#pragma unroll
      for (int r = 0; r < 4; r++)
        pb[(l4 * 4 + r) * 232 + ct * 16 + l15] = f2bf(sc[ct][r]);
#pragma unroll
    for (int r = 0; r < 4; r++)
      pb[(l4 * 4 + r) * 232 + 208 + l15] = 0;

    short8 pa[7];
#pragma unroll
    for (int kk = 0; kk < 7; kk++)
      pa[kk] = *(const short8*)&pb[l15 * 232 + kk * 32 + (l4 << 3)];
    f32x4 o[4];
    __builtin_amdgcn_s_setprio(1);
#pragma unroll
    for (int dt = 0; dt < 4; dt++) {
      f32x4 acc = (f32x4)0.0f;
#pragma unroll
      for (int kk = 0; kk < 7; kk++) {
        short8 bv = *(const short8*)&Vt[(dt * 16 + l15) * 232 + kk * 32 + (l4 << 3)];
        acc = MFMA16(pa[kk], bv, acc);
      }
      o[dt] = acc;
    }
    __builtin_amdgcn_s_setprio(0);

    float rs[4];
#pragma unroll
    for (int r = 0; r < 4; r++) rs[r] = 1.0f / sum[r];
#pragma unroll
    for (int dt = 0; dt < 4; dt++) {
#pragma unroll
      for (int r = 0; r < 4; r++) {
        int row = q0 + l4 * 4 + r;
        if (row < 197) {
          float v = o[dt][r] * rs[r];
          aout[(size_t)(b * 197 + row) * 768 + h * 64 + dt * 16 + l15] = f2bf(v);
        }
      }
    }
  }
}

extern "C" void kernel_launch(void* const* d_in, const int* in_sizes, int n_in,
                              void* d_out, int out_size, void* d_ws, size_t ws_size,
                              hipStream_t stream) {
  const float* x      = (const float*)d_in[0];
  const float* w_qkv  = (const float*)d_in[1];
  const float* w_proj = (const float*)d_in[2];
  const float* b_proj = (const float*)d_in[3];
  const float* rpb    = (const float*)d_in[4];
  const int*   relidx = (const int*)d_in[5];
  float* out = (float*)d_out;

  char* ws = (char*)d_ws;
  const size_t HB = (size_t)12608 * 768 * 2;  // 19,365,888 B
  ushort* xbf   = (ushort*)(ws);              // aliased by aout after qkv is consumed
  ushort* qws   = (ushort*)(ws + HB);
  ushort* kws   = (ushort*)(ws + 2 * HB);
  ushort* vws   = (ushort*)(ws + 3 * HB);
  float*  bias  = (float*)(ws + 4 * HB);                       // 2,076,672 B
  ushort* wqkvb = (ushort*)(ws + 4 * HB + 2076672);            // 3,538,944 B
  ushort* wprjb = (ushort*)(ws + 4 * HB + 2076672 + 3538944);  // 1,179,648 B
  ushort* aout  = xbf;

  hipLaunchKernelGGL(prep_all, dim3(7908), dim3(256), 0, stream,
                     rpb, relidx, bias, x, xbf, w_qkv, wqkvb, w_proj, wprjb);
  hipLaunchKernelGGL((qkv256<9>), dim3(9 * 50), dim3(512), 0, stream,
                     xbf, wqkvb, qws, kws, vws);
  hipLaunchKernelGGL(attn, dim3(768), dim3(512), 0, stream, qws, kws, vws, bias, aout);
  hipLaunchKernelGGL(proj128, dim3(6 * 99), dim3(256), 0, stream,
                     aout, wprjb, b_proj, out);
}